// Round 12
// baseline (1088.780 us; speedup 1.0000x reference)
//
#include <hip/hip_runtime.h>

#define N_NODES 100000
#define N_EDGES 1600000
#define DIM 128
#define NLAYERS 3
#define NGRAPHS 512
#define BN_EPS 1e-5f

#define SCHUNK 512                                  // nodes per scan block
#define SBLOCKS ((N_NODES + SCHUNK - 1) / SCHUNK)   // 196

#define WPLANE 16384                 // shorts per W plane [128 n][128 k]
#define LSTRIDE (4 * WPLANE)         // shorts per layer: [p][plane][128][128]

#define NRANGE 8                     // dst ranges (XCD-aligned via blockIdx&7)
#define RNODES (N_NODES / NRANGE)    // 12500 nodes per range

typedef __attribute__((ext_vector_type(8))) short short8;
typedef __attribute__((ext_vector_type(4))) float f32x4;

// bf16 helpers (raw ushort bits; RNE convert)
__device__ __forceinline__ unsigned f2b(float f) {
  unsigned u = __float_as_uint(f);
  return (u + 0x7FFFu + ((u >> 16) & 1u)) >> 16;
}
__device__ __forceinline__ float b2f(unsigned hw) {
  return __uint_as_float(hw << 16);
}

// ---------------- CSR build ----------------
__global__ __launch_bounds__(256) void hist_kernel(const int* __restrict__ dst,
                                                   int* __restrict__ deg) {
  for (int e = blockIdx.x * blockDim.x + threadIdx.x; e < N_EDGES;
       e += gridDim.x * blockDim.x)
    atomicAdd(&deg[dst[e]], 1);
}

__global__ __launch_bounds__(256) void partial_kernel(const int* __restrict__ deg,
                                                      int* __restrict__ bsum) {
  __shared__ int red[256];
  const int t = threadIdx.x;
  const int i0 = blockIdx.x * SCHUNK + 2 * t;
  int s = 0;
  if (i0 + 1 < N_NODES) {
    const int2 v = *(const int2*)(deg + i0);
    s = v.x + v.y;
  } else if (i0 < N_NODES) {
    s = deg[i0];
  }
  red[t] = s;
  __syncthreads();
  for (int off = 128; off > 0; off >>= 1) {
    if (t < off) red[t] += red[t + off];
    __syncthreads();
  }
  if (t == 0) bsum[blockIdx.x] = red[0];
}

__global__ __launch_bounds__(256) void bscan_kernel(const int* __restrict__ bsum,
                                                    int* __restrict__ boff,
                                                    int* __restrict__ row_ptr) {
  __shared__ int s[256];
  const int t = threadIdx.x;
  const int v = (t < SBLOCKS) ? bsum[t] : 0;
  s[t] = v;
  __syncthreads();
  for (int off = 1; off < 256; off <<= 1) {
    int u = (t >= off) ? s[t - off] : 0;
    __syncthreads();
    s[t] += u;
    __syncthreads();
  }
  if (t < SBLOCKS) boff[t] = s[t] - v;  // exclusive
  if (t == SBLOCKS - 1) row_ptr[N_NODES] = s[t];
}

__global__ __launch_bounds__(256) void emit_kernel(const int* __restrict__ deg,
                                                   const int* __restrict__ boff,
                                                   int* __restrict__ row_ptr,
                                                   int* __restrict__ cursor) {
  __shared__ int s[256];
  const int t = threadIdx.x;
  const int i0 = blockIdx.x * SCHUNK + 2 * t;
  int d0 = 0, d1 = 0;
  if (i0 + 1 < N_NODES) {
    const int2 v = *(const int2*)(deg + i0);
    d0 = v.x; d1 = v.y;
  } else if (i0 < N_NODES) {
    d0 = deg[i0];
  }
  const int pair = d0 + d1;
  s[t] = pair;
  __syncthreads();
  for (int off = 1; off < 256; off <<= 1) {
    int u = (t >= off) ? s[t - off] : 0;
    __syncthreads();
    s[t] += u;
    __syncthreads();
  }
  const int base = boff[blockIdx.x] + s[t] - pair;
  if (i0 + 1 < N_NODES) {
    const int2 rp = make_int2(base, base + d0);
    *(int2*)(row_ptr + i0) = rp;
    *(int2*)(cursor + i0) = rp;
  } else if (i0 < N_NODES) {
    row_ptr[i0] = base;
    cursor[i0] = base;
  }
}

// dst-ranged fill (validated R11: kills 16x write-amp; WRITE 107MB -> L2-coalesced)
__global__ __launch_bounds__(256) void fill_kernel(const int* __restrict__ src,
                                                   const int* __restrict__ dst,
                                                   int* __restrict__ cursor,
                                                   int* __restrict__ col) {
  const int r = blockIdx.x & (NRANGE - 1);
  const int lo = r * RNODES;
  const int hi = lo + RNODES;
  const int nb = gridDim.x >> 3;   // blocks per range group
  const int bi = blockIdx.x >> 3;  // index within range group
  for (int e = bi * 256 + threadIdx.x; e < N_EDGES; e += nb * 256) {
    const int d = dst[e];
    if (d >= lo && d < hi) {
      const int pos = atomicAdd(&cursor[d], 1);
      col[pos] = src[e];
    }
  }
}

// ---------------- x -> bf16 shadow (once per call) ----------------
__global__ __launch_bounds__(256) void xcvt_kernel(const float* __restrict__ x,
                                                   ushort* __restrict__ zb) {
  const int i = blockIdx.x * 256 + threadIdx.x;  // exactly N*DIM/8 threads
  const float4 a = ((const float4*)x)[2 * i];
  const float4 b = ((const float4*)x)[2 * i + 1];
  uint4 o;
  o.x = (f2b(a.y) << 16) | f2b(a.x);
  o.y = (f2b(a.w) << 16) | f2b(a.z);
  o.z = (f2b(b.y) << 16) | f2b(b.x);
  o.w = (f2b(b.w) << 16) | f2b(b.z);
  ((uint4*)zb)[i] = o;
}

// ---------------- weights: transpose + split-bf16 (once per call) ----------------
// wsplit layer l = [p(W1/W2)][plane(hi/lo)][128 n][128 k], contiguous WPLANE each
__global__ __launch_bounds__(256) void wcvt_kernel(const float* __restrict__ W1,
                                                   const float* __restrict__ W2,
                                                   ushort* __restrict__ wsplit) {
  const int id = blockIdx.x * 256 + threadIdx.x;  // 3*2*128*128 = 98304
  const int k = id & 127;
  const int n = (id >> 7) & 127;
  const int p = (id >> 14) & 1;
  const int l = id >> 15;
  const float* src = p ? W2 : W1;
  const float v = src[(size_t)l * WPLANE + k * 128 + n];
  const unsigned hi = f2b(v);
  const unsigned lo = f2b(v - b2f(hi));
  ushort* dst = wsplit + (size_t)l * LSTRIDE + (size_t)p * 2 * WPLANE + n * 128 + k;
  dst[0] = (ushort)hi;
  dst[WPLANE] = (ushort)lo;
}

// ---- aggregation: bf16 gather, f32 accumulate, hi/lo bf16 planes out ----
__global__ __launch_bounds__(256) void agg_kernel(const ushort* __restrict__ zb,
                                                  const int* __restrict__ row_ptr,
                                                  const int* __restrict__ col,
                                                  ushort* __restrict__ aggh,
                                                  ushort* __restrict__ aggl) {
  const int w = (blockIdx.x * 256 + threadIdx.x) >> 6;  // one wave per node
  const int lane = threadIdx.x & 63;
  if (w >= N_NODES) return;
  const int start = row_ptr[w];
  const int end = row_ptr[w + 1];

  const unsigned us = ((const unsigned*)(zb + (size_t)w * 128))[lane];  // self
  float ax = b2f(us & 0xFFFFu), ay = b2f(us >> 16);
  int j = start;
  for (; j + 8 <= end; j += 8) {
    const int c0 = col[j], c1 = col[j + 1], c2 = col[j + 2], c3 = col[j + 3];
    const int c4 = col[j + 4], c5 = col[j + 5], c6 = col[j + 6], c7 = col[j + 7];
    const unsigned u0 = ((const unsigned*)(zb + (size_t)c0 * 128))[lane];
    const unsigned u1 = ((const unsigned*)(zb + (size_t)c1 * 128))[lane];
    const unsigned u2 = ((const unsigned*)(zb + (size_t)c2 * 128))[lane];
    const unsigned u3 = ((const unsigned*)(zb + (size_t)c3 * 128))[lane];
    const unsigned u4 = ((const unsigned*)(zb + (size_t)c4 * 128))[lane];
    const unsigned u5 = ((const unsigned*)(zb + (size_t)c5 * 128))[lane];
    const unsigned u6 = ((const unsigned*)(zb + (size_t)c6 * 128))[lane];
    const unsigned u7 = ((const unsigned*)(zb + (size_t)c7 * 128))[lane];
    ax += ((b2f(u0 & 0xFFFFu) + b2f(u1 & 0xFFFFu)) + (b2f(u2 & 0xFFFFu) + b2f(u3 & 0xFFFFu))) +
          ((b2f(u4 & 0xFFFFu) + b2f(u5 & 0xFFFFu)) + (b2f(u6 & 0xFFFFu) + b2f(u7 & 0xFFFFu)));
    ay += ((b2f(u0 >> 16) + b2f(u1 >> 16)) + (b2f(u2 >> 16) + b2f(u3 >> 16))) +
          ((b2f(u4 >> 16) + b2f(u5 >> 16)) + (b2f(u6 >> 16) + b2f(u7 >> 16)));
  }
  for (; j + 4 <= end; j += 4) {
    const int c0 = col[j], c1 = col[j + 1], c2 = col[j + 2], c3 = col[j + 3];
    const unsigned u0 = ((const unsigned*)(zb + (size_t)c0 * 128))[lane];
    const unsigned u1 = ((const unsigned*)(zb + (size_t)c1 * 128))[lane];
    const unsigned u2 = ((const unsigned*)(zb + (size_t)c2 * 128))[lane];
    const unsigned u3 = ((const unsigned*)(zb + (size_t)c3 * 128))[lane];
    ax += (b2f(u0 & 0xFFFFu) + b2f(u1 & 0xFFFFu)) + (b2f(u2 & 0xFFFFu) + b2f(u3 & 0xFFFFu));
    ay += (b2f(u0 >> 16) + b2f(u1 >> 16)) + (b2f(u2 >> 16) + b2f(u3 >> 16));
  }
  for (; j < end; ++j) {
    const unsigned uc = ((const unsigned*)(zb + (size_t)col[j] * 128))[lane];
    ax += b2f(uc & 0xFFFFu);
    ay += b2f(uc >> 16);
  }
  const unsigned hx = f2b(ax), hy = f2b(ay);
  const unsigned lx = f2b(ax - b2f(hx)), ly = f2b(ay - b2f(hy));
  ((unsigned*)(aggh + (size_t)w * 128))[lane] = (hy << 16) | hx;
  ((unsigned*)(aggl + (size_t)w * 128))[lane] = (ly << 16) | lx;
}

// ---------------- split-bf16 MFMA MLP, W direct global->reg ----------------
// block = 256 thr = 4 waves; 64 rows; wave wv owns rows [16wv,16wv+16).
// A-frag: lane l -> row l&15, k = 8*(l>>4)+j ; B-frag: lane l -> col l&15, same k.
// D: lane l reg r -> row (l>>4)*4+r, col l&15.
// B-frags read straight from L2-resident wsplit (16 rows x 64B aligned segs per
// instr, coalesced) -> no Wc LDS, no staging barriers; LDS = h1 only (34.8KB,
// 4 blocks/CU). Waves touch only their own 16 h1 rows -> no inter-wave barrier.
__global__ __launch_bounds__(256, 4) void mlp_kernel(
    const ushort* __restrict__ Xhp,   // aggh [N][128] bf16 hi plane
    const ushort* __restrict__ Xlp,   // aggl [N][128] bf16 lo plane
    const ushort* __restrict__ Wsp,   // layer base: [p][plane][128 n][128 k]
    const float* __restrict__ b1,
    const float* __restrict__ b2,
    float* __restrict__ out,          // d_out, row stride 384
    int lcol,
    float* __restrict__ bnsum) {      // [256]: sum | sumsq
  __shared__ __align__(16) ushort smem[2 * 64 * 136];  // h1 hi/lo, 34816 B
  ushort* Hh = smem;
  ushort* Hl = smem + 64 * 136;
  float* red = (float*)smem;  // epilogue overlay (16x128 f32 = 8KB)

  const int tid = threadIdx.x;
  const int l = tid & 63, wv = tid >> 6;
  const int lr = l & 15, lg = l >> 4;
  const int n0 = blockIdx.x * 64;
  // clamp OOB rows (garbage stays in its own D-row; stores are guarded)
  const int arow = min(n0 + wv * 16 + lr, N_NODES - 1);
  const size_t abase = (size_t)arow * 128 + lg * 8;
  const int bbase = lr * 128 + lg * 8;  // B-frag lane offset within a plane

  f32x4 acc[8];
#pragma unroll
  for (int nt = 0; nt < 8; ++nt) acc[nt] = {0.f, 0.f, 0.f, 0.f};

  // ---- phase 1: A from global aggh/aggl, B from global W1 planes ----
  {
    const ushort* Wh = Wsp;           // W1 hi
    const ushort* Wl = Wsp + WPLANE;  // W1 lo
#pragma unroll
    for (int kc = 0; kc < 4; ++kc) {
      const short8 ah = *(const short8*)(Xhp + abase + kc * 32);
      const short8 al = *(const short8*)(Xlp + abase + kc * 32);
#pragma unroll
      for (int nt = 0; nt < 8; ++nt) {
        const short8 bh = *(const short8*)(Wh + nt * 2048 + bbase + kc * 32);
        const short8 bl = *(const short8*)(Wl + nt * 2048 + bbase + kc * 32);
        acc[nt] = __builtin_amdgcn_mfma_f32_16x16x32_bf16(ah, bh, acc[nt], 0, 0, 0);
        acc[nt] = __builtin_amdgcn_mfma_f32_16x16x32_bf16(al, bh, acc[nt], 0, 0, 0);
        acc[nt] = __builtin_amdgcn_mfma_f32_16x16x32_bf16(ah, bl, acc[nt], 0, 0, 0);
      }
    }
  }

  // h1 = relu(acc + b1) -> Hh/Hl (own rows only; no barrier needed)
  {
#pragma unroll
    for (int nt = 0; nt < 8; ++nt) {
      const float b1v = b1[nt * 16 + lr];
#pragma unroll
      for (int r = 0; r < 4; ++r) {
        const float h = fmaxf(acc[nt][r] + b1v, 0.f);
        const unsigned hi = f2b(h);
        const unsigned lo = f2b(h - b2f(hi));
        Hh[(wv * 16 + lg * 4 + r) * 136 + nt * 16 + lr] = (ushort)hi;
        Hl[(wv * 16 + lg * 4 + r) * 136 + nt * 16 + lr] = (ushort)lo;
      }
      acc[nt] = {0.f, 0.f, 0.f, 0.f};
    }
  }

  // ---- phase 2: A from LDS h1 (own rows), B from global W2 planes ----
  {
    const ushort* Wh = Wsp + 2 * WPLANE;  // W2 hi
    const ushort* Wl = Wsp + 3 * WPLANE;  // W2 lo
    const int hrow = (wv * 16 + lr) * 136 + lg * 8;
#pragma unroll
    for (int kc = 0; kc < 4; ++kc) {
      const short8 ah = *(const short8*)(Hh + hrow + kc * 32);
      const short8 al = *(const short8*)(Hl + hrow + kc * 32);
#pragma unroll
      for (int nt = 0; nt < 8; ++nt) {
        const short8 bh = *(const short8*)(Wh + nt * 2048 + bbase + kc * 32);
        const short8 bl = *(const short8*)(Wl + nt * 2048 + bbase + kc * 32);
        acc[nt] = __builtin_amdgcn_mfma_f32_16x16x32_bf16(ah, bh, acc[nt], 0, 0, 0);
        acc[nt] = __builtin_amdgcn_mfma_f32_16x16x32_bf16(al, bh, acc[nt], 0, 0, 0);
        acc[nt] = __builtin_amdgcn_mfma_f32_16x16x32_bf16(ah, bl, acc[nt], 0, 0, 0);
      }
    }
  }

  // epilogue: relu(acc + b2) -> out, BN partials
  float s[8], q2[8];
  {
#pragma unroll
    for (int nt = 0; nt < 8; ++nt) { s[nt] = 0.f; q2[nt] = 0.f; }
#pragma unroll
    for (int nt = 0; nt < 8; ++nt) {
      const float b2v = b2[nt * 16 + lr];
#pragma unroll
      for (int r = 0; r < 4; ++r) {
        const int n = n0 + wv * 16 + lg * 4 + r;
        const float h = fmaxf(acc[nt][r] + b2v, 0.f);
        if (n < N_NODES) {
          out[(size_t)n * (NLAYERS * DIM) + lcol + nt * 16 + lr] = h;
          s[nt] += h;
          q2[nt] += h * h;
        }
      }
    }
  }
  __syncthreads();  // all h1 LDS reads done; red overlays smem

  const int rg = tid >> 4, cb = tid & 15;
#pragma unroll
  for (int nt = 0; nt < 8; ++nt) red[rg * 128 + nt * 16 + cb] = s[nt];
  __syncthreads();
  if (tid < 128) {
    float t = 0.f;
#pragma unroll
    for (int g = 0; g < 16; ++g) t += red[g * 128 + tid];
    unsafeAtomicAdd(&bnsum[tid], t);
  }
  __syncthreads();
#pragma unroll
  for (int nt = 0; nt < 8; ++nt) red[rg * 128 + nt * 16 + cb] = q2[nt];
  __syncthreads();
  if (tid < 128) {
    float t = 0.f;
#pragma unroll
    for (int g = 0; g < 16; ++g) t += red[g * 128 + tid];
    unsafeAtomicAdd(&bnsum[128 + tid], t);
  }
}

// ---------------- BN finalize + normalize ----------------
__global__ __launch_bounds__(128) void bn_finalize_kernel(
    const float* __restrict__ bnsum, const float* __restrict__ gamma,
    const float* __restrict__ beta, float* __restrict__ bnfin) {
  const int c = threadIdx.x;
  const float inv_n = 1.f / (float)N_NODES;
  const float mu = bnsum[c] * inv_n;
  const float var = bnsum[128 + c] * inv_n - mu * mu;
  const float inv = rsqrtf(var + BN_EPS);
  const float sc = gamma[c] * inv;
  bnfin[c] = sc;
  bnfin[128 + c] = beta[c] - mu * sc;
}

// normalize f32 column block in-place; optionally emit bf16 z for next gather
__global__ __launch_bounds__(256) void bn_norm_kernel(float* __restrict__ zcol,
                                                      const float* __restrict__ bnfin,
                                                      ushort* __restrict__ zb) {
  const int idx = blockIdx.x * 256 + threadIdx.x;
  if (idx >= N_NODES * 32) return;
  const int n = idx >> 5, c4 = idx & 31;
  const float4 sc = ((const float4*)bnfin)[c4];
  const float4 sh = ((const float4*)(bnfin + 128))[c4];
  float4* p = (float4*)(zcol + (size_t)n * (NLAYERS * DIM)) + c4;
  float4 v = *p;
  v.x = fmaf(v.x, sc.x, sh.x);
  v.y = fmaf(v.y, sc.y, sh.y);
  v.z = fmaf(v.z, sc.z, sh.z);
  v.w = fmaf(v.w, sc.w, sh.w);
  *p = v;
  if (zb) {
    uint2 o;
    o.x = (f2b(v.y) << 16) | f2b(v.x);
    o.y = (f2b(v.w) << 16) | f2b(v.z);
    *(uint2*)(zb + (size_t)n * 128 + c4 * 4) = o;
  }
}

// ---------------- graph pooling (batch is sorted) ----------------
__global__ __launch_bounds__(128) void pool_kernel(const float* __restrict__ zout,
                                                   const int* __restrict__ batch,
                                                   float* __restrict__ gout) {
  const int g = blockIdx.x / 3;
  const int chunk = blockIdx.x % 3;
  const int c = chunk * 128 + threadIdx.x;
  int lo = 0, hi = N_NODES;
  while (lo < hi) {
    const int m = (lo + hi) >> 1;
    if (batch[m] < g) lo = m + 1; else hi = m;
  }
  int lo2 = lo, hi2 = N_NODES;
  while (lo2 < hi2) {
    const int m = (lo2 + hi2) >> 1;
    if (batch[m] < g + 1) lo2 = m + 1; else hi2 = m;
  }
  float acc = 0.f;
  for (int n = lo; n < lo2; ++n) acc += zout[(size_t)n * (NLAYERS * DIM) + c];
  gout[(size_t)g * (NLAYERS * DIM) + c] = acc;
}

// ---------------- launch ----------------
extern "C" void kernel_launch(void* const* d_in, const int* in_sizes, int n_in,
                              void* d_out, int out_size, void* d_ws, size_t ws_size,
                              hipStream_t stream) {
  const float* x = (const float*)d_in[0];
  const int* ei = (const int*)d_in[1];
  const int* src = ei;
  const int* dst = ei + N_EDGES;
  const int* batch = (const int*)d_in[2];
  const float* W1 = (const float*)d_in[3];
  const float* b1 = (const float*)d_in[4];
  const float* W2 = (const float*)d_in[5];
  const float* b2 = (const float*)d_in[6];
  const float* gamma = (const float*)d_in[7];
  const float* beta = (const float*)d_in[8];
  float* out = (float*)d_out;
  float* gout = out + (size_t)N_NODES * NLAYERS * DIM;

  char* ws = (char*)d_ws;
  size_t off = 0;
  auto alloc = [&](size_t bytes) -> void* {
    off = (off + 511) & ~(size_t)511;
    void* p = ws + off;
    off += bytes;
    return p;
  };
  int* row_ptr = (int*)alloc((N_NODES + 1) * sizeof(int));
  int* cursor = (int*)alloc(N_NODES * sizeof(int));
  int* deg = (int*)alloc(N_NODES * sizeof(int));
  int* col = (int*)alloc(N_EDGES * sizeof(int));
  int* bsum = (int*)alloc(SBLOCKS * sizeof(int));
  int* boff = (int*)alloc(SBLOCKS * sizeof(int));
  ushort* zb = (ushort*)alloc((size_t)N_NODES * 128 * sizeof(ushort));
  ushort* aggh = (ushort*)alloc((size_t)N_NODES * 128 * sizeof(ushort));
  ushort* aggl = (ushort*)alloc((size_t)N_NODES * 128 * sizeof(ushort));
  ushort* wsplit = (ushort*)alloc((size_t)NLAYERS * LSTRIDE * sizeof(ushort));
  float* bnsum = (float*)alloc(NLAYERS * 256 * sizeof(float));
  float* bnfin = (float*)alloc(NLAYERS * 256 * sizeof(float));

  hipMemsetAsync(deg, 0, N_NODES * sizeof(int), stream);
  hipMemsetAsync(bnsum, 0, NLAYERS * 256 * sizeof(float), stream);

  hist_kernel<<<2048, 256, 0, stream>>>(dst, deg);
  partial_kernel<<<SBLOCKS, 256, 0, stream>>>(deg, bsum);
  bscan_kernel<<<1, 256, 0, stream>>>(bsum, boff, row_ptr);
  emit_kernel<<<SBLOCKS, 256, 0, stream>>>(deg, boff, row_ptr, cursor);
  fill_kernel<<<2048, 256, 0, stream>>>(src, dst, cursor, col);
  xcvt_kernel<<<(N_NODES * DIM / 8) / 256, 256, 0, stream>>>(x, zb);
  wcvt_kernel<<<384, 256, 0, stream>>>(W1, W2, wsplit);

  for (int l = 0; l < NLAYERS; ++l) {
    agg_kernel<<<(N_NODES * 64 + 255) / 256, 256, 0, stream>>>(zb, row_ptr, col,
                                                               aggh, aggl);
    mlp_kernel<<<(N_NODES + 63) / 64, 256, 0, stream>>>(
        aggh, aggl, wsplit + (size_t)l * LSTRIDE, b1 + (size_t)l * DIM,
        b2 + (size_t)l * DIM, out, l * DIM, bnsum + l * 256);
    bn_finalize_kernel<<<1, 128, 0, stream>>>(bnsum + l * 256, gamma + l * DIM,
                                              beta + l * DIM, bnfin + l * 256);
    bn_norm_kernel<<<(N_NODES * 32 + 255) / 256, 256, 0, stream>>>(
        out + (size_t)l * DIM, bnfin + l * 256, (l < NLAYERS - 1) ? zb : nullptr);
  }
  pool_kernel<<<NGRAPHS * 3, 128, 0, stream>>>(out, batch, gout);
}